// Round 6
// baseline (372.086 us; speedup 1.0000x reference)
//
#include <hip/hip_runtime.h>

typedef __bf16 v8bf __attribute__((ext_vector_type(8)));
typedef __bf16 v4bf __attribute__((ext_vector_type(4)));
typedef float floatx4 __attribute__((ext_vector_type(4)));

#define MFMA16(a, b, c) __builtin_amdgcn_mfma_f32_16x16x32_bf16(a, b, c, 0, 0, 0)
// async global->LDS, 16B/lane; LDS dest = wave-uniform base + lane*16
#define GLL16(gp, lp)                                                        \
    __builtin_amdgcn_global_load_lds(                                        \
        (const __attribute__((address_space(1))) void*)(gp),                 \
        (__attribute__((address_space(3))) void*)(lp), 16, 0, 0)
// counted vmcnt + raw barrier (asm w/ memory clobber: no compiler drain,
// no load motion across)
#define VMW(n) asm volatile("s_waitcnt vmcnt(" #n ")" ::: "memory")
#define BARRIER() asm volatile("s_barrier" ::: "memory")

// ---------------------------------------------------------------- cast x -> bf16
__global__ void cast_x(const float* __restrict__ x, __bf16* __restrict__ xb, int n4) {
    int i = blockIdx.x * blockDim.x + threadIdx.x;
    int stride = gridDim.x * blockDim.x;
    for (; i < n4; i += stride) {
        float4 v = ((const float4*)x)[i];
        v4bf o;
        o[0] = (__bf16)v.x; o[1] = (__bf16)v.y; o[2] = (__bf16)v.z; o[3] = (__bf16)v.w;
        ((v4bf*)xb)[i] = o;
    }
}

// ---------------------- transpose + cast ALL weights (K-contiguous), one launch
__global__ void transW(const float* __restrict__ W0, const float* __restrict__ W1,
                       const float* __restrict__ W2, const float* __restrict__ W3,
                       __bf16* __restrict__ dqkv, __bf16* __restrict__ dwo) {
    __shared__ __bf16 tile[64][65];
    int k0 = blockIdx.x * 64;
    int byy = blockIdx.y;
    bool isO = byy >= 24;
    int c0 = (isO ? byy - 24 : byy) * 64;
    for (int i = threadIdx.x; i < 4096; i += 256) {
        int k = i >> 6, c = i & 63;
        int gc = c0 + c;
        float v;
        if (isO)            v = W3[(k0 + k) * 1024 + gc];
        else if (gc < 1024) v = W0[(k0 + k) * 1024 + gc];
        else if (gc < 1280) v = W1[(k0 + k) * 256 + gc - 1024];
        else                v = W2[(k0 + k) * 256 + gc - 1280];
        tile[c][k] = (__bf16)v;
    }
    __syncthreads();
    __bf16* dst = isO ? dwo : dqkv;
    for (int i = threadIdx.x; i < 4096; i += 256) {
        int c = i >> 6, k = i & 63;
        dst[(c0 + c) * 1024 + k0 + k] = tile[c][k];
    }
}

// -------------------- GEMM (NT, bf16 MFMA), 4-wave blocks, SLOTS-deep LDS
// C[M][N] = A[M][1024] * B[N][1024]^T.  Tile 128(M) x 256(N), 256 thr =
// 4 waves, each wave owns a 128x64 C-panel (FLOP/LDS-byte 42.7).
// R6: the stall-coverage lever is INDEPENDENT BARRIER CHAINS per CU
// (R3: 1->2 chains = 74->64us).  SLOTS=2 -> 48KB LDS -> 3 blocks/CU
// (3 chains, 12 waves) AND exact-round grids (768 = 256x3).  Prefetch
// depth = SLOTS-1 (counted VMW, never 0 mid-loop).  SLOTS=3 (72KB,
// 2 blocks/CU, depth-2) kept for the Wo GEMM whose 512-block grid is
// already an exact 2-per-CU round.
template <int SLOTS, typename OUT>
__global__ __launch_bounds__(256, SLOTS == 2 ? 3 : 2)
void gemm_bt(const __bf16* __restrict__ A, const __bf16* __restrict__ B,
             OUT* __restrict__ C, int N) {
    constexpr int SLAB = (128 + 256) * 32;           // 12288 elems = 24KB
    constexpr int DEPTH = SLOTS - 1;
    __shared__ __attribute__((aligned(16))) __bf16 smem[SLOTS * SLAB];
    const int t = threadIdx.x, lane = t & 63, w = t >> 6;
    // XCD-contiguous swizzle (nwg % 8 == 0 for both launches -> bijective)
    const int gx = gridDim.x;
    const int nwg = gx * gridDim.y;
    const int id = blockIdx.y * gx + blockIdx.x;
    const int swz = (id & 7) * (nwg >> 3) + (id >> 3);
    const int m0 = (swz / gx) * 128, n0 = (swz % gx) * 256;
    const int wn = w * 64;                            // wave's C columns
    const int rl = lane >> 2;                         // row within 16-row chunk
    const int gl = (lane & 3) ^ ((lane >> 3) & 3);    // global-side swizzle
    const __bf16* pA = A + (long)(m0 + w * 32 + rl) * 1024 + gl * 8;
    const __bf16* pB = B + (long)(n0 + w * 64 + rl) * 1024 + gl * 8;
    const int lr = lane & 15, quad = lane >> 4, m = lane & 15;
    const int ga = ((quad ^ ((lr >> 1) & 3)) * 8);    // read-side swizzle
    floatx4 acc[8][4] = {};

    auto STAGE = [&](int s) {
        __bf16* base = smem + (s % SLOTS) * SLAB;
        const __bf16* sa = pA + s * 32;
        const __bf16* sb = pB + s * 32;
        GLL16(sa,             base + w * 1024);
        GLL16(sa + 16 * 1024, base + w * 1024 + 512);
        __bf16* bb = base + 4096;                     // B region
        GLL16(sb,             bb + w * 2048);
        GLL16(sb + 16 * 1024, bb + w * 2048 + 512);
        GLL16(sb + 32 * 1024, bb + w * 2048 + 1024);
        GLL16(sb + 48 * 1024, bb + w * 2048 + 1536);
    };
    auto COMPUTE = [&](int s) {
        const __bf16* As_ = smem + (s % SLOTS) * SLAB;
        const __bf16* Bs_ = As_ + 4096;
        v8bf af[8], bq[4];
#pragma unroll
        for (int i = 0; i < 8; ++i)
            af[i] = *(const v8bf*)(As_ + (i * 16 + lr) * 32 + ga);
#pragma unroll
        for (int j = 0; j < 4; ++j)
            bq[j] = *(const v8bf*)(Bs_ + (wn + j * 16 + lr) * 32 + ga);
        __builtin_amdgcn_s_setprio(1);
#pragma unroll
        for (int i = 0; i < 8; ++i)
#pragma unroll
            for (int j = 0; j < 4; ++j)
                acc[i][j] = MFMA16(af[i], bq[j], acc[i][j]);
        __builtin_amdgcn_s_setprio(0);
    };

    if constexpr (DEPTH == 2) { STAGE(0); STAGE(1); }
    else                      { STAGE(0); }
#pragma unroll 1
    for (int s = 0; s < 32 - DEPTH; ++s) {
        STAGE(s + DEPTH);                // into slot consumed DEPTH phases ago
        if constexpr (DEPTH == 2) VMW(12); else VMW(6);  // slab s landed
        BARRIER();
        COMPUTE(s);
        BARRIER();
    }
    if constexpr (DEPTH == 2) {
        VMW(6);  BARRIER(); COMPUTE(30); BARRIER();
    }
    VMW(0);  BARRIER(); COMPUTE(31);
    __syncthreads();

    // epilogue: per-wave LDS transpose -> coalesced 16-elem stores
    const int row2 = lane >> 2, cb = lane & 3;
    if constexpr (sizeof(OUT) == 2) {          // bf16 out, stride-68 tile
        __bf16* tile = smem + w * (16 * 68);
#pragma unroll
        for (int i = 0; i < 8; ++i) {
#pragma unroll
            for (int j = 0; j < 4; ++j)
#pragma unroll
                for (int r = 0; r < 4; ++r)
                    tile[(quad * 4 + r) * 68 + j * 16 + m] = (__bf16)acc[i][j][r];
            __bf16* dst = (__bf16*)C + (long)(m0 + i * 16 + row2) * N + n0 + wn + cb * 16;
            *(v8bf*)dst = *(const v8bf*)(&tile[row2 * 68 + cb * 16]);
            *(v8bf*)(dst + 8) = *(const v8bf*)(&tile[row2 * 68 + cb * 16 + 8]);
        }
    } else {                                    // fp32 out, stride-66 tile
        float* tile = (float*)smem + w * (16 * 66);
#pragma unroll
        for (int i = 0; i < 8; ++i) {
#pragma unroll
            for (int j = 0; j < 4; ++j)
#pragma unroll
                for (int r = 0; r < 4; ++r)
                    tile[(quad * 4 + r) * 66 + j * 16 + m] = acc[i][j][r];
            float* dst = (float*)C + (long)(m0 + i * 16 + row2) * N + n0 + wn + cb * 16;
#pragma unroll
            for (int c = 0; c < 4; ++c)
                *(floatx4*)(dst + c * 4) = *(const floatx4*)(&tile[row2 * 66 + cb * 16 + c * 4]);
        }
    }
}

// ------------------------------------------------- RMSNorm + RoPE for K only
__global__ __launch_bounds__(256) void knorm(const __bf16* __restrict__ qkv,
                                             const float* __restrict__ rc,
                                             const float* __restrict__ rs,
                                             const float* __restrict__ ksc,
                                             __bf16* __restrict__ Kb) {
    int item = blockIdx.x * 4 + (threadIdx.x >> 6);
    int lane = threadIdx.x & 63;
    int row = item >> 2, hk = item & 3;
    int n = row >> 8, s = row & 255;
    float v = (float)qkv[(long)row * 1536 + 1024 + hk * 64 + lane];
    float sq = v * v;
#pragma unroll
    for (int msk = 1; msk < 64; msk <<= 1) sq += __shfl_xor(sq, msk);
    float rr = rsqrtf(sq * (1.f / 64.f) + 1e-6f);
    v = v * rr * ksc[lane];
    float c = rc[s * 32 + (lane & 31)];
    float sn = rs[s * 32 + (lane & 31)];
    float p = __shfl_xor(v, 32);
    v = (lane < 32) ? (v * c - p * sn) : (v * c + p * sn);
    Kb[((long)((n * 4 + hk) * 256 + s) << 6) + lane] = (__bf16)v;
}

// ---------------------------------------------------------------- attention
// R5-proven: V^T slot permutation perm = sgi ^ (hd&7) ^ (hd>>3) satisfies
// both the staging-write lane shape (cg=hd>>3 varies) and the PV-read lane
// shape (hd&7=m&7 varies): write = 2 same-dword lanes/bank (free), read =
// the b128 8-cycle minimum.  Unchanged this round.
__global__ __launch_bounds__(512) void attn_kernel(const __bf16* __restrict__ qkv,
                                                   const __bf16* __restrict__ Kb,
                                                   const float* __restrict__ rc,
                                                   const float* __restrict__ rs,
                                                   const float* __restrict__ qsc,
                                                   __bf16* __restrict__ O) {
    __shared__ __attribute__((aligned(16))) __bf16 KV[256 * 64];  // K, then V^T
    __shared__ __attribute__((aligned(16))) __bf16 Ps[8][16][40];
    const int bx = blockIdx.x;
    const int n = bx >> 5, h = (bx >> 1) & 15, half = bx & 1, hk = h >> 2;
    const int t = threadIdx.x, lane = t & 63, w = t >> 6;
    const int m = lane & 15, quad = lane >> 4;

    // stage K[n][hk] rows [s][hd], 8-elem groups swizzled by s&7
    for (int p = 0; p < 4; ++p) {
        int l = t + p * 512;
        int s = l >> 3, cg = l & 7;
        v8bf kv = *(const v8bf*)(Kb + ((long)((n * 4 + hk) * 256 + s) << 6) + cg * 8);
        *(v8bf*)(&KV[s * 64 + ((cg ^ (s & 7)) * 8)]) = kv;
    }
    // Q frag: load raw q, then rmsnorm+rope in-register
    const int srow = half * 128 + w * 16 + m;
    const __bf16* qp = qkv + (long)(n * 256 + srow) * 1536 + h * 64 + quad * 8;
    v8bf qr0 = *(const v8bf*)(qp);
    v8bf qr1 = *(const v8bf*)(qp + 32);
    float f0[8], f1[8], ss = 0.f;
#pragma unroll
    for (int j = 0; j < 8; ++j) {
        f0[j] = (float)qr0[j]; f1[j] = (float)qr1[j];
        ss += f0[j] * f0[j] + f1[j] * f1[j];
    }
    ss += __shfl_xor(ss, 16);
    ss += __shfl_xor(ss, 32);
    float rr = rsqrtf(ss * (1.f / 64.f) + 1e-6f);
    v8bf qa0, qa1;
#pragma unroll
    for (int j = 0; j < 8; ++j) {
        int hd = quad * 8 + j;
        float t1 = f0[j] * rr * qsc[hd];
        float t2 = f1[j] * rr * qsc[32 + hd];
        float c = rc[srow * 32 + hd], sn = rs[srow * 32 + hd];
        qa0[j] = (__bf16)(t1 * c - t2 * sn);
        qa1[j] = (__bf16)(t2 * c + t1 * sn);
    }
    __syncthreads();

    floatx4 sc[16];
#pragma unroll
    for (int ti = 0; ti < 16; ++ti) {
        int kr = ti * 16 + m;
        v8bf b0 = *(const v8bf*)(&KV[kr * 64 + ((quad ^ (kr & 7)) * 8)]);
        v8bf b1 = *(const v8bf*)(&KV[kr * 64 + (((quad + 4) ^ (kr & 7)) * 8)]);
        floatx4 a = {0.f, 0.f, 0.f, 0.f};
        a = MFMA16(qa0, b0, a);
        a = MFMA16(qa1, b1, a);
        sc[ti] = a;
    }

    // p = exp(50*tanh(v*0.0025)) ; bounded -> no max-subtract; 1/sum deferred
    const int qbase = half * 128 + w * 16 + quad * 4;
    float sum[4] = {0.f, 0.f, 0.f, 0.f};
#pragma unroll
    for (int ti = 0; ti < 16; ++ti)
#pragma unroll
        for (int r = 0; r < 4; ++r) {
            float v = sc[ti][r];
            float e = __builtin_amdgcn_exp2f(v * 0.0072134752f);
            float capped = 50.f - 100.f * __builtin_amdgcn_rcpf(e + 1.f);
            float p = __builtin_amdgcn_exp2f(capped * 1.44269504f);
            if (ti == 15 && (qbase + r) < 240) p = 0.f;
            sc[ti][r] = p;
            sum[r] += p;
        }
    float inv[4];
#pragma unroll
    for (int r = 0; r < 4; ++r) {
#pragma unroll
        for (int msk = 1; msk < 16; msk <<= 1) sum[r] += __shfl_xor(sum[r], msk);
        inv[r] = __builtin_amdgcn_rcpf(sum[r]);
    }

    // stage V^T over K's LDS: Vt[hd][s]; slot perm = sgi ^ (hd&7) ^ (hd>>3)
    __syncthreads();
    for (int p = 0; p < 4; ++p) {
        int l = t + p * 512;
        int s = l >> 3, cg = l & 7;
        v8bf vv = *(const v8bf*)(qkv + (long)(n * 256 + s) * 1536 + 1280 + hk * 64 + cg * 8);
#pragma unroll
        for (int j = 0; j < 8; ++j)
            KV[(cg * 8 + j) * 256 + (((s >> 3) ^ j ^ cg) * 8) + (s & 7)] = vv[j];
    }
    __syncthreads();

    floatx4 oacc[4] = {};
#pragma unroll
    for (int kc = 0; kc < 8; ++kc) {
#pragma unroll
        for (int ht = 0; ht < 2; ++ht) {
            int ti = kc * 2 + ht;
#pragma unroll
            for (int r = 0; r < 4; ++r)
                Ps[w][quad * 4 + r][ht * 16 + m] = (__bf16)sc[ti][r];
        }
        v8bf pa = *(const v8bf*)(&Ps[w][m][quad * 8]);
#pragma unroll
        for (int ct = 0; ct < 4; ++ct) {
            int hd = ct * 16 + m;
            int sg = kc * 4 + quad;
            int sl = (sg ^ (hd & 7) ^ (hd >> 3)) & 31;
            v8bf vb = *(const v8bf*)(&KV[hd * 256 + sl * 8]);
            oacc[ct] = MFMA16(pa, vb, oacc[ct]);
        }
    }
#pragma unroll
    for (int ct = 0; ct < 4; ++ct)
#pragma unroll
        for (int r = 0; r < 4; ++r) {
            int qrow = half * 128 + w * 16 + quad * 4 + r;
            O[(long)(n * 256 + qrow) * 1024 + h * 64 + ct * 16 + m] =
                (__bf16)(oacc[ct][r] * inv[r]);
        }
}

// ---------------------------------------------------------------- launch
extern "C" void kernel_launch(void* const* d_in, const int* in_sizes, int n_in,
                              void* d_out, int out_size, void* d_ws, size_t ws_size,
                              hipStream_t stream) {
    const float* x  = (const float*)d_in[0];
    const float* rc = (const float*)d_in[2];
    const float* rs = (const float*)d_in[3];
    const float* Wq = (const float*)d_in[4];
    const float* Wk = (const float*)d_in[5];
    const float* Wv = (const float*)d_in[6];
    const float* Wo = (const float*)d_in[7];
    const float* qs = (const float*)d_in[8];
    const float* ks = (const float*)d_in[9];
    float* out = (float*)d_out;
    char* ws = (char*)d_ws;

    __bf16* x_bf    = (__bf16*)(ws);                       // 32MB
    __bf16* WqkvT   = (__bf16*)(ws + (32l << 20));         // 3MB  [1536][1024]
    __bf16* WoT     = (__bf16*)(ws + (35l << 20));         // 2MB  [1024][1024]
    __bf16* qkv_bf  = (__bf16*)(ws + (37l << 20));         // 48MB [16384][1536]
    __bf16* K_bf    = (__bf16*)(ws + (85l << 20));         // 8MB  [n][hk][s][64]
    __bf16* attn_bf = (__bf16*)(ws + (93l << 20));         // 32MB [16384][1024]

    cast_x<<<4096, 256, 0, stream>>>(x, x_bf, 16777216 / 4);
    transW<<<dim3(16, 40), 256, 0, stream>>>(Wq, Wk, Wv, Wo, WqkvT, WoT);
    // QKV: SLOTS=2 (48KB) -> 3 blocks/CU, 768 blocks = EXACT 3-per-CU round
    gemm_bt<2, __bf16><<<dim3(6, 128), 256, 0, stream>>>(x_bf, WqkvT, qkv_bf, 1536);
    knorm<<<16384, 256, 0, stream>>>(qkv_bf, rc, rs, ks, K_bf);
    attn_kernel<<<2048, 512, 0, stream>>>(qkv_bf, K_bf, rc, rs, qs, attn_bf);
    // Wo: SLOTS=3 (72KB) -> 2 blocks/CU, 512 blocks = exact round (unchanged)
    gemm_bt<3, float><<<dim3(4, 128), 256, 0, stream>>>(attn_bf, WoT, out, 1024);
}

// Round 7
// 305.747 us; speedup vs baseline: 1.2170x; 1.2170x over previous
//
#include <hip/hip_runtime.h>

typedef __bf16 v8bf __attribute__((ext_vector_type(8)));
typedef __bf16 v4bf __attribute__((ext_vector_type(4)));
typedef float floatx4 __attribute__((ext_vector_type(4)));

#define MFMA16(a, b, c) __builtin_amdgcn_mfma_f32_16x16x32_bf16(a, b, c, 0, 0, 0)
// async global->LDS, 16B/lane; LDS dest = wave-uniform base + lane*16
#define GLL16(gp, lp)                                                        \
    __builtin_amdgcn_global_load_lds(                                        \
        (const __attribute__((address_space(1))) void*)(gp),                 \
        (__attribute__((address_space(3))) void*)(lp), 16, 0, 0)
// counted vmcnt + raw barrier (asm w/ memory clobber: no compiler drain,
// no load motion across)
#define VMW(n) asm volatile("s_waitcnt vmcnt(" #n ")" ::: "memory")
#define BARRIER() asm volatile("s_barrier" ::: "memory")

// ------------------- prep: cast x -> bf16  AND  transpose/cast weights
// one launch; blocks [0,640) do the weight transpose, the rest cast x.
__global__ void prep(const float* __restrict__ x, __bf16* __restrict__ xb, int n4,
                     const float* __restrict__ W0, const float* __restrict__ W1,
                     const float* __restrict__ W2, const float* __restrict__ W3,
                     __bf16* __restrict__ dqkv, __bf16* __restrict__ dwo) {
    __shared__ __bf16 tile[64][65];
    int b = blockIdx.x;
    if (b < 640) {                         // ---- transW job (16 x 40)
        int k0 = (b & 15) * 64;
        int byy = b >> 4;
        bool isO = byy >= 24;
        int c0 = (isO ? byy - 24 : byy) * 64;
        for (int i = threadIdx.x; i < 4096; i += 256) {
            int k = i >> 6, c = i & 63;
            int gc = c0 + c;
            float v;
            if (isO)            v = W3[(k0 + k) * 1024 + gc];
            else if (gc < 1024) v = W0[(k0 + k) * 1024 + gc];
            else if (gc < 1280) v = W1[(k0 + k) * 256 + gc - 1024];
            else                v = W2[(k0 + k) * 256 + gc - 1280];
            tile[c][k] = (__bf16)v;
        }
        __syncthreads();
        __bf16* dst = isO ? dwo : dqkv;
        for (int i = threadIdx.x; i < 4096; i += 256) {
            int c = i >> 6, k = i & 63;
            dst[(c0 + c) * 1024 + k0 + k] = tile[c][k];
        }
    } else {                               // ---- cast_x job (grid-stride)
        int i = (b - 640) * 256 + threadIdx.x;
        int stride = (gridDim.x - 640) * 256;
        for (; i < n4; i += stride) {
            float4 v = ((const float4*)x)[i];
            v4bf o;
            o[0] = (__bf16)v.x; o[1] = (__bf16)v.y; o[2] = (__bf16)v.z; o[3] = (__bf16)v.w;
            ((v4bf*)xb)[i] = o;
        }
    }
}

// -------------------- GEMM (NT, bf16 MFMA), 4-wave blocks, 2 blocks/CU
// C[M][N] = A[M][1024] * B[N][1024]^T.  Tile 128(M) x 256(N), 256 thr =
// 4 waves, each wave owns a 128x64 C-panel (FLOP/LDS-byte 42.7).
// 72KB LDS (3 slots x 24KB) -> 2 independent blocks co-resident per CU
// (R3: 1->2 barrier chains = 74->64us).  K: 32 slabs of 32; depth-2 GLL
// pipeline, counted VMW(12); setprio around MFMAs.
// R6 LESSON (do not revisit): __launch_bounds__(256,3) to get 3 blocks/CU
// caps regs at 168 < the ~224 this wave-tile needs -> acc spills to
// scratch in the K-loop (WRITE_SIZE 49->219MB, dur 2x).  (256,2) is the
// max-geometry point: 96 VGPR + 128 AGPR, zero spill, 810-820 TF.
template <typename OUT>
__global__ __launch_bounds__(256, 2) void gemm_bt(const __bf16* __restrict__ A,
                                                  const __bf16* __restrict__ B,
                                                  OUT* __restrict__ C, int N) {
    constexpr int SLAB = (128 + 256) * 32;           // 12288 elems = 24KB
    __shared__ __attribute__((aligned(16))) __bf16 smem[3 * SLAB];  // 72KB
    const int t = threadIdx.x, lane = t & 63, w = t >> 6;
    // XCD-contiguous swizzle (nwg % 8 == 0 for both launches -> bijective)
    const int gx = gridDim.x;
    const int nwg = gx * gridDim.y;
    const int id = blockIdx.y * gx + blockIdx.x;
    const int swz = (id & 7) * (nwg >> 3) + (id >> 3);
    const int m0 = (swz / gx) * 128, n0 = (swz % gx) * 256;
    const int wn = w * 64;                            // wave's C columns
    const int rl = lane >> 2;                         // row within 16-row chunk
    const int gl = (lane & 3) ^ ((lane >> 3) & 3);    // global-side swizzle
    const __bf16* pA = A + (long)(m0 + w * 32 + rl) * 1024 + gl * 8;
    const __bf16* pB = B + (long)(n0 + w * 64 + rl) * 1024 + gl * 8;
    const int lr = lane & 15, quad = lane >> 4, m = lane & 15;
    const int ga = ((quad ^ ((lr >> 1) & 3)) * 8);    // read-side swizzle
    floatx4 acc[8][4] = {};

    auto STAGE = [&](int s) {
        __bf16* base = smem + (s % 3) * SLAB;
        const __bf16* sa = pA + s * 32;
        const __bf16* sb = pB + s * 32;
        GLL16(sa,             base + w * 1024);
        GLL16(sa + 16 * 1024, base + w * 1024 + 512);
        __bf16* bb = base + 4096;                     // B region
        GLL16(sb,             bb + w * 2048);
        GLL16(sb + 16 * 1024, bb + w * 2048 + 512);
        GLL16(sb + 32 * 1024, bb + w * 2048 + 1024);
        GLL16(sb + 48 * 1024, bb + w * 2048 + 1536);
    };
    auto COMPUTE = [&](int s) {
        const __bf16* As_ = smem + (s % 3) * SLAB;
        const __bf16* Bs_ = As_ + 4096;
        v8bf af[8], bq[4];
#pragma unroll
        for (int i = 0; i < 8; ++i)
            af[i] = *(const v8bf*)(As_ + (i * 16 + lr) * 32 + ga);
#pragma unroll
        for (int j = 0; j < 4; ++j)
            bq[j] = *(const v8bf*)(Bs_ + (wn + j * 16 + lr) * 32 + ga);
        __builtin_amdgcn_s_setprio(1);
#pragma unroll
        for (int i = 0; i < 8; ++i)
#pragma unroll
            for (int j = 0; j < 4; ++j)
                acc[i][j] = MFMA16(af[i], bq[j], acc[i][j]);
        __builtin_amdgcn_s_setprio(0);
    };

    STAGE(0); STAGE(1);
#pragma unroll 1
    for (int s = 0; s < 30; ++s) {
        STAGE(s + 2);                    // slot (s+2)%3, read 2 phases ago
        VMW(12);                         // slab s landed
        BARRIER();
        COMPUTE(s);
        BARRIER();
    }
    VMW(6);  BARRIER(); COMPUTE(30); BARRIER();
    VMW(0);  BARRIER(); COMPUTE(31);
    __syncthreads();

    // epilogue: per-wave LDS transpose -> coalesced 16-elem stores
    const int row2 = lane >> 2, cb = lane & 3;
    if constexpr (sizeof(OUT) == 2) {          // bf16 out, stride-68 tile
        __bf16* tile = smem + w * (16 * 68);
#pragma unroll
        for (int i = 0; i < 8; ++i) {
#pragma unroll
            for (int j = 0; j < 4; ++j)
#pragma unroll
                for (int r = 0; r < 4; ++r)
                    tile[(quad * 4 + r) * 68 + j * 16 + m] = (__bf16)acc[i][j][r];
            __bf16* dst = (__bf16*)C + (long)(m0 + i * 16 + row2) * N + n0 + wn + cb * 16;
            *(v8bf*)dst = *(const v8bf*)(&tile[row2 * 68 + cb * 16]);
            *(v8bf*)(dst + 8) = *(const v8bf*)(&tile[row2 * 68 + cb * 16 + 8]);
        }
    } else {                                    // fp32 out, stride-66 tile
        float* tile = (float*)smem + w * (16 * 66);
#pragma unroll
        for (int i = 0; i < 8; ++i) {
#pragma unroll
            for (int j = 0; j < 4; ++j)
#pragma unroll
                for (int r = 0; r < 4; ++r)
                    tile[(quad * 4 + r) * 66 + j * 16 + m] = acc[i][j][r];
            float* dst = (float*)C + (long)(m0 + i * 16 + row2) * N + n0 + wn + cb * 16;
#pragma unroll
            for (int c = 0; c < 4; ++c)
                *(floatx4*)(dst + c * 4) = *(const floatx4*)(&tile[row2 * 66 + cb * 16 + c * 4]);
        }
    }
}

// ---------------------------------------------------------------- attention
// R5-proven V^T slot permutation perm = sgi ^ (hd&7) ^ (hd>>3) (write: 2
// same-dword lanes/bank = free; read: b128 8-cycle minimum).
// R7: K RMSNorm+RoPE FUSED into the K-staging pass (knorm kernel and the
// K_bf round-trip eliminated).  Lane layout makes it cheap: the 8 lanes
// holding one K-row are consecutive (cg = lane&7), so row-sumsq is
// shfl_xor(1,2,4); the RoPE partner hd^32 lives at lane^4, same j.
// Same f32 math and the same bf16 rounding point as the old knorm.
__global__ __launch_bounds__(512) void attn_kernel(const __bf16* __restrict__ qkv,
                                                   const float* __restrict__ rc,
                                                   const float* __restrict__ rs,
                                                   const float* __restrict__ qsc,
                                                   const float* __restrict__ ksc,
                                                   __bf16* __restrict__ O) {
    __shared__ __attribute__((aligned(16))) __bf16 KV[256 * 64];  // K, then V^T
    __shared__ __attribute__((aligned(16))) __bf16 Ps[8][16][40];
    const int bx = blockIdx.x;
    const int n = bx >> 5, h = (bx >> 1) & 15, half = bx & 1, hk = h >> 2;
    const int t = threadIdx.x, lane = t & 63, w = t >> 6;
    const int m = lane & 15, quad = lane >> 4;

    // stage K rows [s][hd] with fused rmsnorm+rope, swizzled by s&7
    for (int p = 0; p < 4; ++p) {
        int l = t + p * 512;
        int s = l >> 3, cg = l & 7;
        v8bf kv = *(const v8bf*)(qkv + (long)(n * 256 + s) * 1536 + 1024 + hk * 64 + cg * 8);
        float f[8], ss2 = 0.f;
#pragma unroll
        for (int j = 0; j < 8; ++j) { f[j] = (float)kv[j]; ss2 += f[j] * f[j]; }
        ss2 += __shfl_xor(ss2, 1);
        ss2 += __shfl_xor(ss2, 2);
        ss2 += __shfl_xor(ss2, 4);
        float krr = rsqrtf(ss2 * (1.f / 64.f) + 1e-6f);
        float vs[8];
#pragma unroll
        for (int j = 0; j < 8; ++j) vs[j] = f[j] * krr * ksc[cg * 8 + j];
        v8bf outv;
#pragma unroll
        for (int j = 0; j < 8; ++j) {
            float pv = __shfl_xor(vs[j], 4);          // partner hd^32
            int hd = cg * 8 + j;
            float c = rc[s * 32 + (hd & 31)], sn = rs[s * 32 + (hd & 31)];
            outv[j] = (__bf16)((cg < 4) ? (vs[j] * c - pv * sn)
                                        : (vs[j] * c + pv * sn));
        }
        *(v8bf*)(&KV[s * 64 + ((cg ^ (s & 7)) * 8)]) = outv;
    }
    // Q frag: load raw q, then rmsnorm+rope in-register
    const int srow = half * 128 + w * 16 + m;
    const __bf16* qp = qkv + (long)(n * 256 + srow) * 1536 + h * 64 + quad * 8;
    v8bf qr0 = *(const v8bf*)(qp);
    v8bf qr1 = *(const v8bf*)(qp + 32);
    float f0[8], f1[8], ss = 0.f;
#pragma unroll
    for (int j = 0; j < 8; ++j) {
        f0[j] = (float)qr0[j]; f1[j] = (float)qr1[j];
        ss += f0[j] * f0[j] + f1[j] * f1[j];
    }
    ss += __shfl_xor(ss, 16);
    ss += __shfl_xor(ss, 32);
    float rr = rsqrtf(ss * (1.f / 64.f) + 1e-6f);
    v8bf qa0, qa1;
#pragma unroll
    for (int j = 0; j < 8; ++j) {
        int hd = quad * 8 + j;
        float t1 = f0[j] * rr * qsc[hd];
        float t2 = f1[j] * rr * qsc[32 + hd];
        float c = rc[srow * 32 + hd], sn = rs[srow * 32 + hd];
        qa0[j] = (__bf16)(t1 * c - t2 * sn);
        qa1[j] = (__bf16)(t2 * c + t1 * sn);
    }
    __syncthreads();

    floatx4 sc[16];
#pragma unroll
    for (int ti = 0; ti < 16; ++ti) {
        int kr = ti * 16 + m;
        v8bf b0 = *(const v8bf*)(&KV[kr * 64 + ((quad ^ (kr & 7)) * 8)]);
        v8bf b1 = *(const v8bf*)(&KV[kr * 64 + (((quad + 4) ^ (kr & 7)) * 8)]);
        floatx4 a = {0.f, 0.f, 0.f, 0.f};
        a = MFMA16(qa0, b0, a);
        a = MFMA16(qa1, b1, a);
        sc[ti] = a;
    }

    // p = exp(50*tanh(v*0.0025)) ; bounded -> no max-subtract; 1/sum deferred
    const int qbase = half * 128 + w * 16 + quad * 4;
    float sum[4] = {0.f, 0.f, 0.f, 0.f};
#pragma unroll
    for (int ti = 0; ti < 16; ++ti)
#pragma unroll
        for (int r = 0; r < 4; ++r) {
            float v = sc[ti][r];
            float e = __builtin_amdgcn_exp2f(v * 0.0072134752f);
            float capped = 50.f - 100.f * __builtin_amdgcn_rcpf(e + 1.f);
            float p = __builtin_amdgcn_exp2f(capped * 1.44269504f);
            if (ti == 15 && (qbase + r) < 240) p = 0.f;
            sc[ti][r] = p;
            sum[r] += p;
        }
    float inv[4];
#pragma unroll
    for (int r = 0; r < 4; ++r) {
#pragma unroll
        for (int msk = 1; msk < 16; msk <<= 1) sum[r] += __shfl_xor(sum[r], msk);
        inv[r] = __builtin_amdgcn_rcpf(sum[r]);
    }

    // stage V^T over K's LDS: Vt[hd][s]; slot perm = sgi ^ (hd&7) ^ (hd>>3)
    __syncthreads();
    for (int p = 0; p < 4; ++p) {
        int l = t + p * 512;
        int s = l >> 3, cg = l & 7;
        v8bf vv = *(const v8bf*)(qkv + (long)(n * 256 + s) * 1536 + 1280 + hk * 64 + cg * 8);
#pragma unroll
        for (int j = 0; j < 8; ++j)
            KV[(cg * 8 + j) * 256 + (((s >> 3) ^ j ^ cg) * 8) + (s & 7)] = vv[j];
    }
    __syncthreads();

    floatx4 oacc[4] = {};
#pragma unroll
    for (int kc = 0; kc < 8; ++kc) {
#pragma unroll
        for (int ht = 0; ht < 2; ++ht) {
            int ti = kc * 2 + ht;
#pragma unroll
            for (int r = 0; r < 4; ++r)
                Ps[w][quad * 4 + r][ht * 16 + m] = (__bf16)sc[ti][r];
        }
        v8bf pa = *(const v8bf*)(&Ps[w][m][quad * 8]);
#pragma unroll
        for (int ct = 0; ct < 4; ++ct) {
            int hd = ct * 16 + m;
            int sg = kc * 4 + quad;
            int sl = (sg ^ (hd & 7) ^ (hd >> 3)) & 31;
            v8bf vb = *(const v8bf*)(&KV[hd * 256 + sl * 8]);
            oacc[ct] = MFMA16(pa, vb, oacc[ct]);
        }
    }
#pragma unroll
    for (int ct = 0; ct < 4; ++ct)
#pragma unroll
        for (int r = 0; r < 4; ++r) {
            int qrow = half * 128 + w * 16 + quad * 4 + r;
            O[(long)(n * 256 + qrow) * 1024 + h * 64 + ct * 16 + m] =
                (__bf16)(oacc[ct][r] * inv[r]);
        }
}

// ---------------------------------------------------------------- launch
extern "C" void kernel_launch(void* const* d_in, const int* in_sizes, int n_in,
                              void* d_out, int out_size, void* d_ws, size_t ws_size,
                              hipStream_t stream) {
    const float* x  = (const float*)d_in[0];
    const float* rc = (const float*)d_in[2];
    const float* rs = (const float*)d_in[3];
    const float* Wq = (const float*)d_in[4];
    const float* Wk = (const float*)d_in[5];
    const float* Wv = (const float*)d_in[6];
    const float* Wo = (const float*)d_in[7];
    const float* qs = (const float*)d_in[8];
    const float* ks = (const float*)d_in[9];
    float* out = (float*)d_out;
    char* ws = (char*)d_ws;

    __bf16* x_bf    = (__bf16*)(ws);                       // 32MB
    __bf16* WqkvT   = (__bf16*)(ws + (32l << 20));         // 3MB  [1536][1024]
    __bf16* WoT     = (__bf16*)(ws + (35l << 20));         // 2MB  [1024][1024]
    __bf16* qkv_bf  = (__bf16*)(ws + (37l << 20));         // 48MB [16384][1536]
    __bf16* attn_bf = (__bf16*)(ws + (93l << 20));         // 32MB [16384][1024]

    // prep: blocks [0,640) transpose/cast weights, [640,4736) cast x
    prep<<<4736, 256, 0, stream>>>(x, x_bf, 16777216 / 4,
                                   Wq, Wk, Wv, Wo, WqkvT, WoT);
    gemm_bt<__bf16><<<dim3(6, 128), 256, 0, stream>>>(x_bf, WqkvT, qkv_bf, 1536);
    attn_kernel<<<2048, 512, 0, stream>>>(qkv_bf, rc, rs, qs, ks, attn_bf);
    gemm_bt<float><<<dim3(4, 128), 256, 0, stream>>>(attn_bf, WoT, out, 1024);
}